// Round 1
// baseline (283.399 us; speedup 1.0000x reference)
//
#include <hip/hip_runtime.h>

typedef _Float16 half_t;
typedef half_t h2 __attribute__((ext_vector_type(2)));
typedef half_t h4 __attribute__((ext_vector_type(4)));
typedef float f4 __attribute__((ext_vector_type(4)));

#define J 10
#define P 16384
#define D 8
#define O 16
#define B 32

#define PTILE 16
#define NB (P / PTILE)           // 1024 blocks, one per p-tile, all 32 b
#define SJO (B * J * O)          // 5120

#define WT_PLS 2576              // bytes per pl slab of Wt: 10j*16o*8d*2B + 16 pad
#define WT_PLH (WT_PLS / 2)      // 1288 halfs
#define XS_OFF (PTILE * WT_PLS)  // 41216 bytes
#define SMEM_BYTES (XS_OFF + PTILE * B * 16)  // + xs (16pl*32b*16B) = 49408
// epilogue s_blk aliases smem: 4*16*164*4 = 41984 B <= 49408  OK

// ---- DPP cross-lane helpers (squash kernel) ----
template <int CTRL>
__device__ __forceinline__ float dpp_mov_f(float v) {
    return __int_as_float(__builtin_amdgcn_update_dpp(
        0, __float_as_int(v), CTRL, 0xF, 0xF, true));
}
__device__ __forceinline__ float row_sum16(float v) {
    v += dpp_mov_f<0xB1>(v);   // quad_perm xor 1
    v += dpp_mov_f<0x4E>(v);   // quad_perm xor 2
    v += dpp_mov_f<0x124>(v);  // row_ror:4
    v += dpp_mov_f<0x128>(v);  // row_ror:8
    return v;
}

__device__ __forceinline__ h2 pkrtz(float a, float b) {
    return __builtin_bit_cast(h2, __builtin_amdgcn_cvt_pkrtz(a, b));
}

// cross-lane adds for the q-group (o-partial) reduction
__device__ __forceinline__ float xor16_add(float v) {
    // ds_swizzle bit-mode: xor_mask=16, and=0x1F -> lane ^ 16 (within 32-lane half)
    int s = __builtin_amdgcn_ds_swizzle(__float_as_int(v), 0x401F);
    return v + __int_as_float(s);
}
__device__ __forceinline__ float xor32_add(float v, int bpa) {
    int s = __builtin_amdgcn_ds_bpermute(bpa, __float_as_int(v));
    return v + __int_as_float(s);
}

union U4H { uint4 u; h2 h[4]; };
union U2H { uint2 u2; h2 h[2]; h4 v; };
union U1H { unsigned u; h2 h; };

// One routing pass. 1024 blocks x 512 threads; block = one 16-p tile, all 32 b.
// W staged fp32->fp16 LDS [pl][j][o][d]; u_hat via v_mfma_f32_16x16x16f16 with
// C[m=o][n=b] (A = W^T from LDS, B = x with k>=8 masked to 0). D-layout puts
// o in registers (4/lane) and b across lanes -> logits are 2x fdot2 + 2
// cross-lane adds; softmax per-lane over j (4x redundant instead of 16x).
__global__ __launch_bounds__(512, 4) void caps_pass(
    const float* __restrict__ x, const float* __restrict__ W,
    const unsigned* __restrict__ vh, float* __restrict__ s_acc, int first)
{
    __shared__ char smem[SMEM_BYTES];
    half_t* Wt = (half_t*)smem;
    half_t* xs = (half_t*)(smem + XS_OFF);
    float* s_blk = (float*)smem;   // aliased after compute

    const int tid = threadIdx.x;
    const int p0 = blockIdx.x * PTILE;

    // ---- stage W tile: fp32 [j][p][d][o] -> fp16 LDS [pl][j][o][d] ----
    {
        const int o4 = tid & 3, d = (tid >> 2) & 7, pl = tid >> 5;
        const float* src = W + (size_t)p0 * (D * O) + (size_t)tid * 4;
        half_t* dst = Wt + pl * WT_PLH + (o4 * 4) * 8 + d;
#pragma unroll
        for (int j = 0; j < J; ++j) {
            float4 f = *(const float4*)(src + (size_t)j * P * (D * O));
            half_t* dj = dst + j * 128;
            dj[0]  = (half_t)f.x;
            dj[8]  = (half_t)f.y;
            dj[16] = (half_t)f.z;
            dj[24] = (half_t)f.w;
        }
    }
    // ---- stage x tile: fp32 -> fp16 LDS [pl][b][d], 32 b ----
    {
        const int bl = tid >> 4, pl = tid & 15;
        const float4* xp = (const float4*)(x + ((size_t)bl * P + p0 + pl) * D);
        float4 a = xp[0], c = xp[1];
        U4H pk;
        pk.h[0] = pkrtz(a.x, a.y);
        pk.h[1] = pkrtz(a.z, a.w);
        pk.h[2] = pkrtz(c.x, c.y);
        pk.h[3] = pkrtz(c.z, c.w);
        *(uint4*)(xs + (size_t)(pl * 32 + bl) * 8) = pk.u;
    }

    const int lane = tid & 63;
    const int wv   = tid >> 6;        // 0..7
    const int bh   = wv >> 2;         // batch half (0/1)
    const int wid2 = wv & 3;          // pl group
    const int bl16 = lane & 15;       // b within half; also o-row for A-frag
    const int q    = lane >> 4;       // k-group / o-reg group
    const unsigned kmask = (q < 2) ? 0xFFFFFFFFu : 0u;  // zero x for k>=8
    const int bpa = ((lane ^ 32) & 63) << 2;

    // Vsum fp16 pairs (written by squash): v[b][j][o], o-pairs; hoisted per wave
    U2H vf[J];
    if (!first) {
        const unsigned* vp = vh + (size_t)(bh * 16 + bl16) * J * 8 + 2 * q;
#pragma unroll
        for (int j = 0; j < J; ++j)
            vf[j].u2 = *(const uint2*)(vp + j * 8);
    }
    __syncthreads();

    f4 acc[J];
#pragma unroll
    for (int j = 0; j < J; ++j) acc[j] = (f4){0.f, 0.f, 0.f, 0.f};
    const f4 zf = (f4){0.f, 0.f, 0.f, 0.f};

#pragma unroll 1
    for (int pi = 0; pi < 4; ++pi) {
        const int pl = wid2 * 4 + pi;

        // B operand: x fragment, k>=8 zeroed
        U2H xv;
        xv.u2 = *(const uint2*)(xs + (size_t)(pl * 32 + bh * 16 + bl16) * 8
                                + 4 * (q & 1));
        xv.u2.x &= kmask;
        xv.u2.y &= kmask;
        const h4 bfrag = xv.v;

        const half_t* wbase = Wt + pl * WT_PLH + bl16 * 8 + 4 * (q & 1);

        h2 uh[J][2];
        float lg[J];
#pragma unroll
        for (int j = 0; j < J; ++j) {
            const h4 af = *(const h4*)(wbase + j * 128);   // A = W^T row o=bl16
            f4 u = __builtin_amdgcn_mfma_f32_16x16x16f16(af, bfrag, zf, 0, 0, 0);
            if (first) {
#pragma unroll
                for (int r = 0; r < 4; ++r)
                    acc[j][r] = fmaf(0.1f, u[r], acc[j][r]);
            } else {
                uh[j][0] = pkrtz(u[0], u[1]);
                uh[j][1] = pkrtz(u[2], u[3]);
                lg[j] = __builtin_amdgcn_fdot2(uh[j][1], vf[j].h[1],
                        __builtin_amdgcn_fdot2(uh[j][0], vf[j].h[0], 0.f, false),
                        false);
            }
        }

        if (!first) {
#pragma unroll
            for (int j = 0; j < J; ++j) lg[j] = xor16_add(lg[j]);
#pragma unroll
            for (int j = 0; j < J; ++j) lg[j] = xor32_add(lg[j], bpa);
            // max-free softmax: |lg| <~ 35 -> exp safe in fp32
            float e[J], Z = 0.f;
#pragma unroll
            for (int j = 0; j < J; ++j) { e[j] = __expf(lg[j]); Z += e[j]; }
            const float rZ = __builtin_amdgcn_rcpf(Z);
#pragma unroll
            for (int j = 0; j < J; ++j) {
                const float c = e[j] * rZ;
                acc[j][0] = fmaf(c, (float)uh[j][0][0], acc[j][0]);
                acc[j][1] = fmaf(c, (float)uh[j][0][1], acc[j][1]);
                acc[j][2] = fmaf(c, (float)uh[j][1][0], acc[j][2]);
                acc[j][3] = fmaf(c, (float)uh[j][1][1], acc[j][3]);
            }
        }
    }

    // ---- epilogue: per-wave partials -> LDS (aliases Wt/xs) -> atomics ----
    // two rounds (bh=0 then bh=1), s_blk = [wid2][bl][164]
    __syncthreads();
#pragma unroll 1
    for (int r = 0; r < 2; ++r) {
        if (bh == r) {
#pragma unroll
            for (int j = 0; j < J; ++j)
                *(f4*)&s_blk[(size_t)(wid2 * 16 + bl16) * 164 + j * 16 + 4 * q]
                    = acc[j];
        }
        __syncthreads();
        for (int t = tid; t < 16 * 160; t += 512) {
            const int bl = t / 160, rr = t - bl * 160;
            const float v = s_blk[bl * 164 + rr] + s_blk[(16 + bl) * 164 + rr]
                          + s_blk[(32 + bl) * 164 + rr] + s_blk[(48 + bl) * 164 + rr];
            atomicAdd(&s_acc[(size_t)(r * 16 + bl) * 160 + rr], v);
        }
        __syncthreads();
    }
}

// v = squash(s); Vsum += v; emit vh (fp16 o-pairs, layout [b][j][o/2]);
// zero s_acc; optionally emit v. One block per b: lane=(o:16, j:16), j<10 active.
__global__ __launch_bounds__(256) void caps_squash(
    float* __restrict__ s_acc, float* __restrict__ Vsum,
    unsigned* __restrict__ vh, float* __restrict__ out, int write_out)
{
    const int b = blockIdx.x;
    const int o = threadIdx.x & 15;
    const int j = threadIdx.x >> 4;
    const bool act = j < J;
    const int idx = (b * J + (act ? j : 0)) * O + o;
    float s = act ? s_acc[idx] : 0.f;
    const float sq = row_sum16(s * s);
    float vnew = 0.f;
    if (act) {
        const float scale = sqrtf(sq) / (1.f + sq);   // |s|^2/((1+|s|^2)|s|)
        const float v = s * scale;
        vnew = Vsum[idx] + v;
        Vsum[idx] = vnew;
        s_acc[idx] = 0.f;
        if (write_out) out[idx] = v;
    }
    const float vpart = __shfl_xor(vnew, 1, 64);      // partner o^1
    if (act && !(o & 1)) {
        U1H t; t.h = pkrtz(vnew, vpart);
        vh[(size_t)(b * J + j) * 8 + (o >> 1)] = t.u;
    }
}

__global__ __launch_bounds__(256) void caps_zero(float* __restrict__ ws)
{
    const int i = blockIdx.x * 256 + threadIdx.x;
    if (i < 2 * SJO) ws[i] = 0.f;   // s_acc + Vsum
}

extern "C" void kernel_launch(void* const* d_in, const int* in_sizes, int n_in,
                              void* d_out, int out_size, void* d_ws, size_t ws_size,
                              hipStream_t stream)
{
    const float* x = (const float*)d_in[0];
    const float* W = (const float*)d_in[1];
    float* out = (float*)d_out;

    float* s_acc = (float*)d_ws;               // SJO floats
    float* Vsum  = s_acc + SJO;                // SJO floats
    unsigned* vh = (unsigned*)(Vsum + SJO);    // B*J*8 dwords (10 KB)

    caps_zero<<<dim3(40), 256, 0, stream>>>(s_acc);

    for (int it = 0; it < 3; ++it) {
        caps_pass<<<dim3(NB), 512, 0, stream>>>(x, W, vh, s_acc, it == 0 ? 1 : 0);
        caps_squash<<<dim3(B), 256, 0, stream>>>(s_acc, Vsum, vh, out, it == 2 ? 1 : 0);
    }
}

// Round 2
// 250.476 us; speedup vs baseline: 1.1314x; 1.1314x over previous
//
#include <hip/hip_runtime.h>

typedef _Float16 half_t;
typedef half_t h2 __attribute__((ext_vector_type(2)));
typedef half_t h4 __attribute__((ext_vector_type(4)));
typedef float f4 __attribute__((ext_vector_type(4)));

#define J 10
#define P 16384
#define D 8
#define O 16
#define B 32

#define PTILE 16
#define NB (P / PTILE)           // 1024 blocks, one per p-tile, all 32 b
#define SJO (B * J * O)          // 5120

#define WT_PLS 2576              // bytes per pl slab of Wt: 10j*16o*8d*2B + 16 pad
#define WT_PLH (WT_PLS / 2)      // 1288 halfs
#define XS_OFF (PTILE * WT_PLS)  // 41216 bytes
#define VL_OFF (XS_OFF + PTILE * B * 16)      // + xs (16pl*32b*16B) = 49408
#define VL_STRIDE 84             // dwords per b-row of vls (80 data + 4 pad)
#define SMEM_BYTES (VL_OFF + B * VL_STRIDE * 4)  // 49408 + 10752 = 60160
// epilogue s_blk aliases smem: 4*16*164*4 = 41984 B <= 60160  OK

// ---- DPP cross-lane helpers (squash kernel) ----
template <int CTRL>
__device__ __forceinline__ float dpp_mov_f(float v) {
    return __int_as_float(__builtin_amdgcn_update_dpp(
        0, __float_as_int(v), CTRL, 0xF, 0xF, true));
}
__device__ __forceinline__ float row_sum16(float v) {
    v += dpp_mov_f<0xB1>(v);   // quad_perm xor 1
    v += dpp_mov_f<0x4E>(v);   // quad_perm xor 2
    v += dpp_mov_f<0x124>(v);  // row_ror:4
    v += dpp_mov_f<0x128>(v);  // row_ror:8
    return v;
}

__device__ __forceinline__ h2 pkrtz(float a, float b) {
    return __builtin_bit_cast(h2, __builtin_amdgcn_cvt_pkrtz(a, b));
}

// cross-lane adds on the VALU pipe (permlane swaps); LDS-pipe fallback
__device__ __forceinline__ float xadd16(float v) {
#if __has_builtin(__builtin_amdgcn_permlane16_swap)
    auto r = __builtin_amdgcn_permlane16_swap(__float_as_uint(v),
                                              __float_as_uint(v), false, false);
    return __uint_as_float(r[0]) + __uint_as_float(r[1]);
#else
    return v + __shfl_xor(v, 16, 64);
#endif
}
__device__ __forceinline__ float xadd32(float v) {
#if __has_builtin(__builtin_amdgcn_permlane32_swap)
    auto r = __builtin_amdgcn_permlane32_swap(__float_as_uint(v),
                                              __float_as_uint(v), false, false);
    return __uint_as_float(r[0]) + __uint_as_float(r[1]);
#else
    return v + __shfl_xor(v, 32, 64);
#endif
}

union U4H { uint4 u; h2 h[4]; };
union U2H { uint2 u2; h2 h[2]; h4 v; };
union U1H { unsigned u; h2 h; };

// One routing pass. 1024 blocks x 512 threads; block = one 16-p tile, all 32 b.
// W staged fp32->fp16 LDS [pl][j][o][d]; u_hat via v_mfma_f32_16x16x16f16 with
// C[m=o][n=b] (A = W^T from LDS, B = x with k>=8 masked to 0). D-layout puts
// o in registers (4/lane) and b across lanes -> logits are 2x fdot2 + 2
// permlane-swap adds; softmax per-lane over j. Vsum (vh) is read from LDS per
// (pi,j) as a transient to keep peak VGPR pressure under the 128 cap (round-1
// spilled: VGPR=64+spill, WRITE_SIZE 46 MB).
__global__ __launch_bounds__(512, 4) void caps_pass(
    const float* __restrict__ x, const float* __restrict__ W,
    const unsigned* __restrict__ vh, float* __restrict__ s_acc, int first)
{
    __shared__ char smem[SMEM_BYTES];
    half_t* Wt = (half_t*)smem;
    half_t* xs = (half_t*)(smem + XS_OFF);
    unsigned* vls = (unsigned*)(smem + VL_OFF);
    float* s_blk = (float*)smem;   // aliased after compute

    const int tid = threadIdx.x;
    const int p0 = blockIdx.x * PTILE;

    // ---- stage W tile: fp32 [j][p][d][o] -> fp16 LDS [pl][j][o][d] ----
    {
        const int o4 = tid & 3, d = (tid >> 2) & 7, pl = tid >> 5;
        const float* src = W + (size_t)p0 * (D * O) + (size_t)tid * 4;
        half_t* dst = Wt + pl * WT_PLH + (o4 * 4) * 8 + d;
#pragma unroll
        for (int j = 0; j < J; ++j) {
            float4 f = *(const float4*)(src + (size_t)j * P * (D * O));
            half_t* dj = dst + j * 128;
            dj[0]  = (half_t)f.x;
            dj[8]  = (half_t)f.y;
            dj[16] = (half_t)f.z;
            dj[24] = (half_t)f.w;
        }
    }
    // ---- stage x tile: fp32 -> fp16 LDS [pl][b][d], 32 b ----
    {
        const int bl = tid >> 4, pl = tid & 15;
        const float4* xp = (const float4*)(x + ((size_t)bl * P + p0 + pl) * D);
        float4 a = xp[0], c = xp[1];
        U4H pk;
        pk.h[0] = pkrtz(a.x, a.y);
        pk.h[1] = pkrtz(a.z, a.w);
        pk.h[2] = pkrtz(c.x, c.y);
        pk.h[3] = pkrtz(c.z, c.w);
        *(uint4*)(xs + (size_t)(pl * 32 + bl) * 8) = pk.u;
    }
    // ---- stage Vsum fp16: vh [b][j][8dw] -> vls [b][j*8 + dw], stride 84 ----
    if (!first && tid < B * J) {
        const int b = tid / J, j = tid - b * J;
        const uint4* s = (const uint4*)(vh + (size_t)tid * 8);
        uint4* dvl = (uint4*)(vls + b * VL_STRIDE + j * 8);
        dvl[0] = s[0];
        dvl[1] = s[1];
    }

    const int lane = tid & 63;
    const int wv   = tid >> 6;        // 0..7
    const int bh   = wv >> 2;         // batch half (0/1)
    const int wid2 = wv & 3;          // pl group
    const int bl16 = lane & 15;       // b within half; also o-row for A-frag
    const int q    = lane >> 4;       // k-group / o-reg group
    const unsigned kmask = (q < 2) ? 0xFFFFFFFFu : 0u;  // zero x for k>=8
    const int vbase = (bh * 16 + bl16) * VL_STRIDE + q * 2;

    __syncthreads();

    f4 acc[J];
#pragma unroll
    for (int j = 0; j < J; ++j) acc[j] = (f4){0.f, 0.f, 0.f, 0.f};
    const f4 zf = (f4){0.f, 0.f, 0.f, 0.f};

#pragma unroll 1
    for (int pi = 0; pi < 4; ++pi) {
        const int pl = wid2 * 4 + pi;

        // B operand: x fragment, k>=8 zeroed
        U2H xv;
        xv.u2 = *(const uint2*)(xs + (size_t)(pl * 32 + bh * 16 + bl16) * 8
                                + 4 * (q & 1));
        xv.u2.x &= kmask;
        xv.u2.y &= kmask;
        const h4 bfrag = xv.v;

        const half_t* wbase = Wt + pl * WT_PLH + bl16 * 8 + 4 * (q & 1);

        h2 uh[J][2];
        float lg[J];
#pragma unroll
        for (int j = 0; j < J; ++j) {
            const h4 af = *(const h4*)(wbase + j * 128);   // A = W^T row o=bl16
            f4 u = __builtin_amdgcn_mfma_f32_16x16x16f16(af, bfrag, zf, 0, 0, 0);
            if (first) {
#pragma unroll
                for (int r = 0; r < 4; ++r)
                    acc[j][r] = fmaf(0.1f, u[r], acc[j][r]);
            } else {
                uh[j][0] = pkrtz(u[0], u[1]);
                uh[j][1] = pkrtz(u[2], u[3]);
                U2H vf;
                vf.u2 = *(const uint2*)(vls + vbase + j * 8);
                lg[j] = __builtin_amdgcn_fdot2(uh[j][1], vf.h[1],
                        __builtin_amdgcn_fdot2(uh[j][0], vf.h[0], 0.f, false),
                        false);
            }
        }

        if (!first) {
#pragma unroll
            for (int j = 0; j < J; ++j) lg[j] = xadd16(lg[j]);
#pragma unroll
            for (int j = 0; j < J; ++j) lg[j] = xadd32(lg[j]);
            // max-free softmax: |lg| <~ 35 -> exp safe in fp32
            float e[J], Z = 0.f;
#pragma unroll
            for (int j = 0; j < J; ++j) { e[j] = __expf(lg[j]); Z += e[j]; }
            const float rZ = __builtin_amdgcn_rcpf(Z);
#pragma unroll
            for (int j = 0; j < J; ++j) {
                const float c = e[j] * rZ;
                acc[j][0] = fmaf(c, (float)uh[j][0][0], acc[j][0]);
                acc[j][1] = fmaf(c, (float)uh[j][0][1], acc[j][1]);
                acc[j][2] = fmaf(c, (float)uh[j][1][0], acc[j][2]);
                acc[j][3] = fmaf(c, (float)uh[j][1][1], acc[j][3]);
            }
        }
    }

    // ---- epilogue: per-wave partials -> LDS (aliases Wt/xs) -> atomics ----
    // two rounds (bh=0 then bh=1), s_blk = [wid2][bl][164]
    __syncthreads();
#pragma unroll 1
    for (int r = 0; r < 2; ++r) {
        if (bh == r) {
#pragma unroll
            for (int j = 0; j < J; ++j)
                *(f4*)&s_blk[(size_t)(wid2 * 16 + bl16) * 164 + j * 16 + 4 * q]
                    = acc[j];
        }
        __syncthreads();
        for (int t = tid; t < 16 * 160; t += 512) {
            const int bl = t / 160, rr = t - bl * 160;
            const float v = s_blk[bl * 164 + rr] + s_blk[(16 + bl) * 164 + rr]
                          + s_blk[(32 + bl) * 164 + rr] + s_blk[(48 + bl) * 164 + rr];
            atomicAdd(&s_acc[(size_t)(r * 16 + bl) * 160 + rr], v);
        }
        __syncthreads();
    }
}

// v = squash(s); Vsum += v; emit vh (fp16 o-pairs, layout [b][j][o/2]);
// zero s_acc; optionally emit v. One block per b: lane=(o:16, j:16), j<10 active.
__global__ __launch_bounds__(256) void caps_squash(
    float* __restrict__ s_acc, float* __restrict__ Vsum,
    unsigned* __restrict__ vh, float* __restrict__ out, int write_out)
{
    const int b = blockIdx.x;
    const int o = threadIdx.x & 15;
    const int j = threadIdx.x >> 4;
    const bool act = j < J;
    const int idx = (b * J + (act ? j : 0)) * O + o;
    float s = act ? s_acc[idx] : 0.f;
    const float sq = row_sum16(s * s);
    float vnew = 0.f;
    if (act) {
        const float scale = sqrtf(sq) / (1.f + sq);   // |s|^2/((1+|s|^2)|s|)
        const float v = s * scale;
        vnew = Vsum[idx] + v;
        Vsum[idx] = vnew;
        s_acc[idx] = 0.f;
        if (write_out) out[idx] = v;
    }
    const float vpart = __shfl_xor(vnew, 1, 64);      // partner o^1
    if (act && !(o & 1)) {
        U1H t; t.h = pkrtz(vnew, vpart);
        vh[(size_t)(b * J + j) * 8 + (o >> 1)] = t.u;
    }
}

__global__ __launch_bounds__(256) void caps_zero(float* __restrict__ ws)
{
    const int i = blockIdx.x * 256 + threadIdx.x;
    if (i < 2 * SJO) ws[i] = 0.f;   // s_acc + Vsum
}

extern "C" void kernel_launch(void* const* d_in, const int* in_sizes, int n_in,
                              void* d_out, int out_size, void* d_ws, size_t ws_size,
                              hipStream_t stream)
{
    const float* x = (const float*)d_in[0];
    const float* W = (const float*)d_in[1];
    float* out = (float*)d_out;

    float* s_acc = (float*)d_ws;               // SJO floats
    float* Vsum  = s_acc + SJO;                // SJO floats
    unsigned* vh = (unsigned*)(Vsum + SJO);    // B*J*8 dwords (10 KB)

    caps_zero<<<dim3(40), 256, 0, stream>>>(s_acc);

    for (int it = 0; it < 3; ++it) {
        caps_pass<<<dim3(NB), 512, 0, stream>>>(x, W, vh, s_acc, it == 0 ? 1 : 0);
        caps_squash<<<dim3(B), 256, 0, stream>>>(s_acc, Vsum, vh, out, it == 2 ? 1 : 0);
    }
}